// Round 3
// baseline (108.107 us; speedup 1.0000x reference)
//
#include <hip/hip_runtime.h>

// B=4, M=8, N=128, D=32, K=2D=H=64
#define BB 4
#define MM 8
#define BM 32
#define NN 128
#define DD 32
#define KK 64
constexpr int ND = NN * DD;   // 4096
constexpr int NK = NN * KK;   // 8192
#define SMALLV 1e-8f

__device__ __forceinline__ float gelu_t(float v) {
    // 0.5*v*(1+tanh(0.79788456*(v+0.044715 v^3))), tanh(u)=1-2/(exp2(u*2.885390)+1)
    float v2 = v * v;
    float u  = v * fmaf(0.044715f, v2, 1.0f) * 0.7978845608028654f;
    float e  = __builtin_amdgcn_exp2f(u * 2.8853900817779268f);
    float r  = __builtin_amdgcn_rcpf(e + 1.0f);
    float th = fmaf(-2.0f, r, 1.0f);
    float hv = 0.5f * v;
    return fmaf(hv, th, hv);
}

// ---------------------------------------------------------------------------
// Kernel 1: per-(b,m) set-norm statistics + row mask. 32 blocks x 512.
// ---------------------------------------------------------------------------
__global__ __launch_bounds__(512) void stats_kernel(
    const float* __restrict__ x, const float* __restrict__ x_size,
    float* __restrict__ statsg, float* __restrict__ maskg)
{
    __shared__ float sAny[NN];
    __shared__ float sRed[8];
    const int t = threadIdx.x, bm = blockIdx.x;
    const float* xp = x + (size_t)bm * ND;
    float v[8];
    float lsum = 0.f;
    #pragma unroll
    for (int s = 0; s < 8; ++s) { v[s] = xp[t + s * 512]; lsum += v[s]; }
    if (t < NN) sAny[t] = 0.f;
    __syncthreads();
    #pragma unroll
    for (int s = 0; s < 8; ++s) if (v[s] != 0.f) sAny[(t + s * 512) >> 5] = 1.f;
    #pragma unroll
    for (int off = 32; off; off >>= 1) lsum += __shfl_xor(lsum, off);
    if ((t & 63) == 0) sRed[t >> 6] = lsum;
    __syncthreads();
    float tot = 0.f;
    #pragma unroll
    for (int w = 0; w < 8; ++w) tot += sRed[w];
    const float denom = x_size[bm >> 3] * (float)DD;
    const float mean  = tot / denom;
    float lsq = 0.f;
    #pragma unroll
    for (int s = 0; s < 8; ++s) {
        float d = v[s] - mean;
        lsq += (sAny[(t + s * 512) >> 5] != 0.f) ? d * d : 0.f;
    }
    #pragma unroll
    for (int off = 32; off; off >>= 1) lsq += __shfl_xor(lsq, off);
    __syncthreads();
    if ((t & 63) == 0) sRed[t >> 6] = lsq;
    __syncthreads();
    float sq = 0.f;
    #pragma unroll
    for (int w = 0; w < 8; ++w) sq += sRed[w];
    const float inv = 1.f / (sqrtf(sq / denom) + SMALLV);
    if (t == 0) { statsg[bm * 2] = mean; statsg[bm * 2 + 1] = inv; }
    if (t < NN) maskg[bm * NN + t] = sAny[t];
}

// ---------------------------------------------------------------------------
// Kernel 2: MLP1 + A1/A2. Grid = bm(32) x nt(16) = 512 blocks x 256.
// All weights staged into LDS with float4 loads; compute reads are LDS
// broadcast / stride-1 (conflict-free).
// ---------------------------------------------------------------------------
__global__ __launch_bounds__(256) void mlp_kernel(
    const float* __restrict__ x, const float* __restrict__ statsg,
    const float* __restrict__ maskg,
    const float* __restrict__ W1a, const float* __restrict__ b1a,
    const float* __restrict__ W1b, const float* __restrict__ b1b,
    const float* __restrict__ W2a, const float* __restrict__ b2a,
    const float* __restrict__ W2b, const float* __restrict__ b2b,
    const float* __restrict__ w3,
    float* __restrict__ x1g, float* __restrict__ A1g, float* __restrict__ A2t,
    float* __restrict__ v2g, float* __restrict__ c3g)
{
    __shared__ float sW1a[DD * KK];   // 8 KB
    __shared__ float sW1b[KK * DD];   // 8 KB
    __shared__ float sW2a[DD * KK];   // 8 KB
    __shared__ float sXn[8 * DD];
    __shared__ float sH[8 * KK];
    __shared__ float sX1[8 * DD];
    __shared__ float sB1a[KK], sB2a[KK], sB1b[DD];

    const int t  = threadIdx.x;
    const int bm = blockIdx.x >> 4;
    const int nt = blockIdx.x & 15;
    const int n0 = nt * 8;
    const float mean = statsg[bm * 2], inv = statsg[bm * 2 + 1];

    // Stage weights: 512 float4 per matrix, 2 per thread
    {
        const float4* a4 = (const float4*)W1a;
        const float4* b4 = (const float4*)W1b;
        const float4* c4 = (const float4*)W2a;
        float4* sa = (float4*)sW1a; float4* sb = (float4*)sW1b; float4* sc = (float4*)sW2a;
        sa[t] = a4[t]; sa[t + 256] = a4[t + 256];
        sb[t] = b4[t]; sb[t + 256] = b4[t + 256];
        sc[t] = c4[t]; sc[t + 256] = c4[t + 256];
    }
    if (t < KK) { sB1a[t] = b1a[t]; sB2a[t] = b2a[t]; }
    if (t < DD) { sB1b[t] = b1b[t]; }

    // Load + normalize 8 rows (256 elements, one per thread)
    {
        float mk = maskg[bm * NN + n0 + (t >> 5)];
        float xv = x[(size_t)bm * ND + n0 * DD + t];
        sXn[t] = (xv - mean) * inv * mk;
    }
    __syncthreads();

    const int k    = t & 63;
    const int slot = t >> 6;       // 0..3 (== wave id)

    // H = gelu(xn @ W1a + b1a): rows slot, slot+4
    #pragma unroll
    for (int r = 0; r < 2; ++r) {
        int n = slot + r * 4;
        const float* xr = &sXn[n * DD];
        float acc = sB1a[k];
        #pragma unroll
        for (int d = 0; d < DD; ++d) acc = fmaf(xr[d], sW1a[d * KK + k], acc);
        sH[n * KK + k] = gelu_t(acc);
    }
    __syncthreads();

    // x1 = (H @ W1b + b1b) * mask: thread = (d, row)
    {
        const int d2 = t & 31;
        const int n  = t >> 5;     // 0..7
        const float* hr = &sH[n * KK];
        float acc = sB1b[d2];
        #pragma unroll
        for (int q = 0; q < KK; ++q) acc = fmaf(hr[q], sW1b[q * DD + d2], acc);
        float val = acc * maskg[bm * NN + n0 + n];
        sX1[n * DD + d2] = val;
        x1g[(size_t)bm * ND + (n0 + n) * DD + d2] = val;
    }
    __syncthreads();

    // A1 = x1@W2a + b2a ; A2 = xn@W2a (transposed store)
    #pragma unroll
    for (int r = 0; r < 2; ++r) {
        int n = slot + r * 4;
        const float* x1r = &sX1[n * DD];
        const float* xnr = &sXn[n * DD];
        float a1 = sB2a[k], a2 = 0.f;
        #pragma unroll
        for (int d = 0; d < DD; ++d) {
            a1 = fmaf(x1r[d], sW2a[d * KK + k], a1);
            a2 = fmaf(xnr[d], sW2a[d * KK + k], a2);
        }
        A1g[(size_t)bm * NK + (n0 + n) * KK + k] = a1;
        A2t[(size_t)bm * NK + k * NN + (n0 + n)] = a2;
    }

    if (blockIdx.x == 0) {
        if (t < KK) {
            float acc = 0.f;
            for (int h = 0; h < KK; ++h) acc += W2b[t * KK + h] * w3[h];
            v2g[t] = acc;
        }
        if (t == 0) {
            float acc = 0.f;
            for (int h = 0; h < KK; ++h) acc += b2b[h] * w3[h];
            c3g[0] = acc;
        }
    }
}

// ---------------------------------------------------------------------------
// Kernel 3: pair interactions. Grid = bm(32) x jg(2) x ig(16) = 1024 blocks.
// 4 waves; each wave handles 2 i's concurrently (2 independent S chains).
// lane = j; a2[64] in regs; A1/x1/v2 broadcast from LDS; acc[32] in regs.
// ---------------------------------------------------------------------------
__global__ __launch_bounds__(256) void pair_kernel(
    const float* __restrict__ A1g, const float* __restrict__ A2t,
    const float* __restrict__ x1g, const float* __restrict__ v2g,
    const float* __restrict__ c3g, float* __restrict__ partial)
{
    __shared__ float sA1[8 * KK];          // 2 KB
    __shared__ float sX1[8 * DD];          // 1 KB
    __shared__ float sV2[KK];
    __shared__ float sPart[4][64][DD + 1]; // 33.8 KB
    const int t    = threadIdx.x;
    const int bm   = blockIdx.x >> 5;
    const int jg   = (blockIdx.x >> 4) & 1;
    const int ig   = blockIdx.x & 15;
    const int w    = t >> 6;
    const int lane = t & 63;

    sA1[t]       = A1g[(size_t)bm * NK + ig * 512 + t];
    sA1[t + 256] = A1g[(size_t)bm * NK + ig * 512 + t + 256];
    sX1[t]       = x1g[(size_t)bm * ND + ig * 256 + t];
    if (t < KK) sV2[t] = v2g[t];
    const float c3 = c3g[0];

    float a2r[KK];
    #pragma unroll
    for (int q = 0; q < KK; ++q)
        a2r[q] = A2t[(size_t)bm * NK + q * NN + jg * 64 + lane];

    float acc[DD];
    #pragma unroll
    for (int d = 0; d < DD; ++d) acc[d] = 0.f;
    __syncthreads();

    const float4* v2f = (const float4*)sV2;
    {
        const int i0 = w * 2, i1 = w * 2 + 1;
        const float4* a1f0 = (const float4*)&sA1[i0 * KK];
        const float4* a1f1 = (const float4*)&sA1[i1 * KK];
        const float4* x1f0 = (const float4*)&sX1[i0 * DD];
        const float4* x1f1 = (const float4*)&sX1[i1 * DD];
        float S0 = c3, S1 = c3;
        #pragma unroll
        for (int kq = 0; kq < 16; ++kq) {
            float4 a0 = a1f0[kq];
            float4 a1 = a1f1[kq];
            float4 vv = v2f[kq];
            S0 = fmaf(gelu_t(a0.x - a2r[kq * 4 + 0]), vv.x, S0);
            S1 = fmaf(gelu_t(a1.x - a2r[kq * 4 + 0]), vv.x, S1);
            S0 = fmaf(gelu_t(a0.y - a2r[kq * 4 + 1]), vv.y, S0);
            S1 = fmaf(gelu_t(a1.y - a2r[kq * 4 + 1]), vv.y, S1);
            S0 = fmaf(gelu_t(a0.z - a2r[kq * 4 + 2]), vv.z, S0);
            S1 = fmaf(gelu_t(a1.z - a2r[kq * 4 + 2]), vv.z, S1);
            S0 = fmaf(gelu_t(a0.w - a2r[kq * 4 + 3]), vv.w, S0);
            S1 = fmaf(gelu_t(a1.w - a2r[kq * 4 + 3]), vv.w, S1);
        }
        #pragma unroll
        for (int dq = 0; dq < 8; ++dq) {
            float4 xa = x1f0[dq];
            float4 xb = x1f1[dq];
            acc[dq * 4 + 0] = fmaf(S0, xa.x, fmaf(S1, xb.x, acc[dq * 4 + 0]));
            acc[dq * 4 + 1] = fmaf(S0, xa.y, fmaf(S1, xb.y, acc[dq * 4 + 1]));
            acc[dq * 4 + 2] = fmaf(S0, xa.z, fmaf(S1, xb.z, acc[dq * 4 + 2]));
            acc[dq * 4 + 3] = fmaf(S0, xa.w, fmaf(S1, xb.w, acc[dq * 4 + 3]));
        }
    }
    #pragma unroll
    for (int d = 0; d < DD; ++d) sPart[w][lane][d] = acc[d];
    __syncthreads();

    const size_t base = (size_t)blockIdx.x * 2048;   // [bm][jg][ig][jl][d]
    #pragma unroll
    for (int s = 0; s < 8; ++s) {
        int idx = t + s * 256;
        int jl = idx >> 5, d = idx & 31;
        partial[base + idx] =
            sPart[0][jl][d] + sPart[1][jl][d] + sPart[2][jl][d] + sPart[3][jl][d];
    }
}

// ---------------------------------------------------------------------------
// Kernel 4: sum 16 i-group partials, add b3 + residual, apply item mask.
// ---------------------------------------------------------------------------
__global__ __launch_bounds__(256) void final_kernel(
    const float* __restrict__ x, const float* __restrict__ b3,
    const float* __restrict__ partial, float* __restrict__ out)
{
    const int gid = blockIdx.x * 256 + threadIdx.x;   // < 131072
    const int j = gid >> 5;
    const int bm = j >> 7, jg = (j >> 6) & 1, jl = j & 63;
    const size_t pb = ((size_t)(bm * 2 + jg) * 16) * 2048 + (jl << 5) + (gid & 31);
    float sum = 0.f;
    #pragma unroll
    for (int ig = 0; ig < 16; ++ig) sum += partial[pb + ig * 2048];
    float xv = x[gid];
    unsigned long long bal = __ballot(xv != 0.f);
    int lane = threadIdx.x & 63;
    unsigned long long half = (lane < 32) ? (bal & 0xFFFFFFFFull) : (bal >> 32);
    float mk = half ? 1.f : 0.f;
    out[gid] = (sum + b3[0] + xv) * mk;
}

extern "C" void kernel_launch(void* const* d_in, const int* in_sizes, int n_in,
                              void* d_out, int out_size, void* d_ws, size_t ws_size,
                              hipStream_t stream) {
    const float* x      = (const float*)d_in[0];
    const float* x_size = (const float*)d_in[1];
    const float* W1a    = (const float*)d_in[2];
    const float* b1a    = (const float*)d_in[3];
    const float* W1b    = (const float*)d_in[4];
    const float* b1b    = (const float*)d_in[5];
    const float* W2a    = (const float*)d_in[6];
    const float* b2a    = (const float*)d_in[7];
    const float* W2b    = (const float*)d_in[8];
    const float* b2b    = (const float*)d_in[9];
    const float* w3     = (const float*)d_in[10];
    const float* b3     = (const float*)d_in[11];
    float* out = (float*)d_out;

    float* ws      = (float*)d_ws;
    float* statsg  = ws;                      // 64
    float* maskg   = statsg + 64;             // 4096
    float* x1g     = maskg + 4096;            // 131072
    float* A1g     = x1g + (size_t)BM * ND;   // 262144
    float* A2t     = A1g + (size_t)BM * NK;   // 262144
    float* v2g     = A2t + (size_t)BM * NK;   // 64
    float* c3g     = v2g + KK;                // 1 (+63 pad)
    float* partial = c3g + 64;                // 1024*2048 = 2097152 (8 MB)

    stats_kernel<<<BM, 512, 0, stream>>>(x, x_size, statsg, maskg);
    mlp_kernel<<<BM * 16, 256, 0, stream>>>(x, statsg, maskg,
        W1a, b1a, W1b, b1b, W2a, b2a, W2b, b2b, w3,
        x1g, A1g, A2t, v2g, c3g);
    pair_kernel<<<BM * 32, 256, 0, stream>>>(A1g, A2t, x1g, v2g, c3g, partial);
    final_kernel<<<512, 256, 0, stream>>>(x, b3, partial, out);
}

// Round 4
// 104.680 us; speedup vs baseline: 1.0327x; 1.0327x over previous
//
#include <hip/hip_runtime.h>

// B=4, M=8, N=128, D=32, K=2D=H=64
#define BMC 32
#define NNC 128
#define DDC 32
#define KKC 64
constexpr int ND = NNC * DDC;   // 4096
constexpr int NK = NNC * KKC;   // 8192
#define SMALLV 1e-8f

__device__ __forceinline__ float gelu_f(float v) {
    // tanh-gelu, constants folded: gelu(v) = v - v * rcp(1 + exp2(v*(a*v^2+b)))
    // b = 2.885390*0.7978846 = 2.3022082, a = b*0.044715 = 0.1029432
    float v2 = v * v;
    float p  = fmaf(0.1029432f, v2, 2.3022082f);
    float e  = __builtin_amdgcn_exp2f(v * p);
    float r  = __builtin_amdgcn_rcpf(e + 1.0f);
    return fmaf(-v, r, v);
}

// ---------------------------------------------------------------------------
// Kernel 1: fused stats + MLP1 + A1/A2. Grid = bm(32) x nt(16) = 512 x 256.
// Each block redundantly computes its (b,m) set-norm stats (cheap), then
// processes its 8-row tile. Weights staged to LDS via float4.
// ---------------------------------------------------------------------------
__global__ __launch_bounds__(256) void mlp_kernel(
    const float* __restrict__ x, const float* __restrict__ x_size,
    const float* __restrict__ W1a, const float* __restrict__ b1a,
    const float* __restrict__ W1b, const float* __restrict__ b1b,
    const float* __restrict__ W2a, const float* __restrict__ b2a,
    const float* __restrict__ W2b, const float* __restrict__ b2b,
    const float* __restrict__ w3,
    float* __restrict__ x1g, float* __restrict__ A1g, float* __restrict__ A2t,
    float* __restrict__ v2g, float* __restrict__ c3g)
{
    __shared__ float sW1a[DDC * KKC];   // 8 KB
    __shared__ float sW1b[KKC * DDC];   // 8 KB
    __shared__ float sW2a[DDC * KKC];   // 8 KB
    __shared__ float sXn[8 * DDC];
    __shared__ float sH[8 * KKC];
    __shared__ float sX1[8 * DDC];
    __shared__ float sB1a[KKC], sB2a[KKC], sB1b[DDC];
    __shared__ float sAny[NNC];
    __shared__ float sRed[4];

    const int t  = threadIdx.x;
    const int bm = blockIdx.x >> 4;
    const int nt = blockIdx.x & 15;
    const int n0 = nt * 8;
    const int w  = t >> 6;

    // Stage weights (512 float4 per matrix, 2 per thread)
    {
        const float4* a4 = (const float4*)W1a;
        const float4* b4 = (const float4*)W1b;
        const float4* c4 = (const float4*)W2a;
        float4* sa = (float4*)sW1a; float4* sb = (float4*)sW1b; float4* sc = (float4*)sW2a;
        sa[t] = a4[t]; sa[t + 256] = a4[t + 256];
        sb[t] = b4[t]; sb[t + 256] = b4[t + 256];
        sc[t] = c4[t]; sc[t + 256] = c4[t + 256];
    }
    if (t < KKC) { sB1a[t] = b1a[t]; sB2a[t] = b2a[t]; }
    if (t < DDC) { sB1b[t] = b1b[t]; }
    if (t < NNC) sAny[t] = 0.f;
    __syncthreads();

    // ---- per-(b,m) stats (redundant per block) ----
    const float4* xs4 = (const float4*)(x + (size_t)bm * ND);
    float4 v4[4];
    float lsum = 0.f;
    #pragma unroll
    for (int s = 0; s < 4; ++s) {
        int f = t + s * 256;
        float4 q = xs4[f];
        v4[s] = q;
        lsum += q.x + q.y + q.z + q.w;
        if (q.x != 0.f || q.y != 0.f || q.z != 0.f || q.w != 0.f) sAny[f >> 3] = 1.f;
    }
    #pragma unroll
    for (int off = 32; off; off >>= 1) lsum += __shfl_xor(lsum, off);
    if ((t & 63) == 0) sRed[w] = lsum;
    __syncthreads();                                  // publishes sAny + sRed(sum)
    const float denom = x_size[bm >> 3] * (float)DDC;
    const float mean  = (sRed[0] + sRed[1] + sRed[2] + sRed[3]) / denom;

    float lsq = 0.f;
    #pragma unroll
    for (int s = 0; s < 4; ++s) {
        int f = t + s * 256;
        float mk = sAny[f >> 3];
        float dx = v4[s].x - mean, dy = v4[s].y - mean;
        float dz = v4[s].z - mean, dw = v4[s].w - mean;
        lsq += mk * (dx * dx + dy * dy + dz * dz + dw * dw);
    }
    #pragma unroll
    for (int off = 32; off; off >>= 1) lsq += __shfl_xor(lsq, off);
    __syncthreads();                                  // done reading sRed(sum)
    if ((t & 63) == 0) sRed[w] = lsq;
    __syncthreads();
    const float sq  = sRed[0] + sRed[1] + sRed[2] + sRed[3];
    const float inv = 1.f / (sqrtf(sq / denom) + SMALLV);

    // ---- normalize own 8-row tile ----
    {
        float xv = x[(size_t)bm * ND + n0 * DDC + t];
        sXn[t] = (xv - mean) * inv * sAny[n0 + (t >> 5)];
    }
    __syncthreads();

    const int k    = t & 63;
    const int slot = w;   // 0..3

    // H = gelu(xn @ W1a + b1a): rows slot, slot+4
    #pragma unroll
    for (int r = 0; r < 2; ++r) {
        int n = slot + r * 4;
        const float* xr = &sXn[n * DDC];
        float acc = sB1a[k];
        #pragma unroll
        for (int d = 0; d < DDC; ++d) acc = fmaf(xr[d], sW1a[d * KKC + k], acc);
        sH[n * KKC + k] = gelu_f(acc);
    }
    __syncthreads();

    // x1 = (H @ W1b + b1b) * mask
    {
        const int d2 = t & 31;
        const int n  = t >> 5;
        const float* hr = &sH[n * KKC];
        float acc = sB1b[d2];
        #pragma unroll
        for (int q = 0; q < KKC; ++q) acc = fmaf(hr[q], sW1b[q * DDC + d2], acc);
        float val = acc * sAny[n0 + n];
        sX1[n * DDC + d2] = val;
        x1g[(size_t)bm * ND + (n0 + n) * DDC + d2] = val;
    }
    __syncthreads();

    // A1 = x1@W2a + b2a ; A2 = xn@W2a (transposed store [k][n])
    #pragma unroll
    for (int r = 0; r < 2; ++r) {
        int n = slot + r * 4;
        const float* x1r = &sX1[n * DDC];
        const float* xnr = &sXn[n * DDC];
        float a1 = sB2a[k], a2 = 0.f;
        #pragma unroll
        for (int d = 0; d < DDC; ++d) {
            a1 = fmaf(x1r[d], sW2a[d * KKC + k], a1);
            a2 = fmaf(xnr[d], sW2a[d * KKC + k], a2);
        }
        A1g[(size_t)bm * NK + (n0 + n) * KKC + k] = a1;
        A2t[(size_t)bm * NK + k * NNC + (n0 + n)] = a2;
    }

    if (blockIdx.x == 0) {
        if (t < KKC) {
            float acc = 0.f;
            for (int h = 0; h < KKC; ++h) acc += W2b[t * KKC + h] * w3[h];
            v2g[t] = acc;
        }
        if (t == 0) {
            float acc = 0.f;
            for (int h = 0; h < KKC; ++h) acc += b2b[h] * w3[h];
            c3g[0] = acc;
        }
    }
}

// ---------------------------------------------------------------------------
// Kernel 2: pair interactions, two-phase. Grid = bm(32) x ig(16) = 512 x 256.
// Phase 1: wave w = (ih, jg); lane = j-local. a2[64] per-lane in VGPRs;
// A1/v2/c3 wave-uniform -> SGPR (s_load); 4 independent S chains; S -> LDS.
// Phase 2: rank-1 update acc[j][d] += S[i,j]*x1[i,d] from LDS; store partial.
// ---------------------------------------------------------------------------
__global__ __launch_bounds__(256) void pair_kernel(
    const float* __restrict__ A1g, const float* __restrict__ A2t,
    const float* __restrict__ x1g, const float* __restrict__ v2g,
    const float* __restrict__ c3g, float* __restrict__ partial)
{
    __shared__ float sS[8 * NNC];    // 4 KB
    __shared__ float sX1[8 * DDC];   // 1 KB
    const int t    = threadIdx.x;
    const int bm   = blockIdx.x >> 4;
    const int ig   = blockIdx.x & 15;
    const int w    = __builtin_amdgcn_readfirstlane(t >> 6);  // wave-uniform
    const int lane = t & 63;
    const int jg   = w & 1;
    const int ih   = w >> 1;
    const int ib   = ig * 8 + ih * 4;   // first of this wave's 4 i's

    // stage x1 tile (8 rows x 32) for phase 2
    sX1[t] = x1g[(size_t)bm * ND + ig * 8 * DDC + t];

    // a2 column for this lane's j (64 coalesced loads)
    const float* A2p = A2t + (size_t)bm * NK + jg * 64 + lane;
    float a2r[KKC];
    #pragma unroll
    for (int q = 0; q < KKC; ++q) a2r[q] = A2p[q * NNC];

    // wave-uniform A1 rows + v2 + c3 -> scalar loads
    const float* a1p0 = A1g + (size_t)bm * NK + (ib + 0) * KKC;
    const float* a1p1 = A1g + (size_t)bm * NK + (ib + 1) * KKC;
    const float* a1p2 = A1g + (size_t)bm * NK + (ib + 2) * KKC;
    const float* a1p3 = A1g + (size_t)bm * NK + (ib + 3) * KKC;
    const float c3 = c3g[0];

    float S0 = c3, S1 = c3, S2 = c3, S3 = c3;
    #pragma unroll
    for (int kk = 0; kk < KKC; ++kk) {
        const float vk = v2g[kk];
        S0 = fmaf(gelu_f(a1p0[kk] - a2r[kk]), vk, S0);
        S1 = fmaf(gelu_f(a1p1[kk] - a2r[kk]), vk, S1);
        S2 = fmaf(gelu_f(a1p2[kk] - a2r[kk]), vk, S2);
        S3 = fmaf(gelu_f(a1p3[kk] - a2r[kk]), vk, S3);
    }
    const int jcol = jg * 64 + lane;
    sS[(ih * 4 + 0) * NNC + jcol] = S0;
    sS[(ih * 4 + 1) * NNC + jcol] = S1;
    sS[(ih * 4 + 2) * NNC + jcol] = S2;
    sS[(ih * 4 + 3) * NNC + jcol] = S3;
    __syncthreads();

    // phase 2: thread = (j = t>>1, d-half = t&1), 16 d's each
    const int j  = t >> 1;
    const int dh = t & 1;
    float acc[16];
    #pragma unroll
    for (int d = 0; d < 16; ++d) acc[d] = 0.f;
    #pragma unroll
    for (int i = 0; i < 8; ++i) {
        float S = sS[i * NNC + j];
        const float4* xf = (const float4*)&sX1[i * DDC + dh * 16];
        #pragma unroll
        for (int q = 0; q < 4; ++q) {
            float4 xv = xf[q];
            acc[q * 4 + 0] = fmaf(S, xv.x, acc[q * 4 + 0]);
            acc[q * 4 + 1] = fmaf(S, xv.y, acc[q * 4 + 1]);
            acc[q * 4 + 2] = fmaf(S, xv.z, acc[q * 4 + 2]);
            acc[q * 4 + 3] = fmaf(S, xv.w, acc[q * 4 + 3]);
        }
    }
    // partial layout: [bm][ig][j][d] ; thread offset = t*16
    float4* pout = (float4*)(partial + ((size_t)(bm * 16 + ig) * NNC) * DDC + (size_t)t * 16);
    #pragma unroll
    for (int q = 0; q < 4; ++q)
        pout[q] = make_float4(acc[q * 4 + 0], acc[q * 4 + 1], acc[q * 4 + 2], acc[q * 4 + 3]);
}

// ---------------------------------------------------------------------------
// Kernel 3: sum 16 i-group partials, add b3 + residual, apply item mask.
// ---------------------------------------------------------------------------
__global__ __launch_bounds__(256) void final_kernel(
    const float* __restrict__ x, const float* __restrict__ b3,
    const float* __restrict__ partial, float* __restrict__ out)
{
    const int gid = blockIdx.x * 256 + threadIdx.x;   // < 131072
    const int bm  = gid >> 12;
    const int rem = gid & 4095;                        // j*32 + d
    const size_t pb = (size_t)bm * 16 * 4096 + rem;
    float sum = 0.f;
    #pragma unroll
    for (int ig = 0; ig < 16; ++ig) sum += partial[pb + (size_t)ig * 4096];
    float xv = x[gid];
    unsigned long long bal = __ballot(xv != 0.f);
    int lane = threadIdx.x & 63;
    unsigned long long half = (lane < 32) ? (bal & 0xFFFFFFFFull) : (bal >> 32);
    float mk = half ? 1.f : 0.f;
    out[gid] = (sum + b3[0] + xv) * mk;
}

extern "C" void kernel_launch(void* const* d_in, const int* in_sizes, int n_in,
                              void* d_out, int out_size, void* d_ws, size_t ws_size,
                              hipStream_t stream) {
    const float* x      = (const float*)d_in[0];
    const float* x_size = (const float*)d_in[1];
    const float* W1a    = (const float*)d_in[2];
    const float* b1a    = (const float*)d_in[3];
    const float* W1b    = (const float*)d_in[4];
    const float* b1b    = (const float*)d_in[5];
    const float* W2a    = (const float*)d_in[6];
    const float* b2a    = (const float*)d_in[7];
    const float* W2b    = (const float*)d_in[8];
    const float* b2b    = (const float*)d_in[9];
    const float* w3     = (const float*)d_in[10];
    const float* b3     = (const float*)d_in[11];
    float* out = (float*)d_out;

    float* ws      = (float*)d_ws;
    float* x1g     = ws;                       // 131072
    float* A1g     = x1g + (size_t)BMC * ND;   // 262144
    float* A2t     = A1g + (size_t)BMC * NK;   // 262144
    float* v2g     = A2t + (size_t)BMC * NK;   // 64
    float* c3g     = v2g + KKC;                // 1 (+63 pad)
    float* partial = c3g + 64;                 // 512*4096 = 2097152 (8 MB)

    mlp_kernel<<<BMC * 16, 256, 0, stream>>>(x, x_size,
        W1a, b1a, W1b, b1b, W2a, b2a, W2b, b2b, w3,
        x1g, A1g, A2t, v2g, c3g);
    pair_kernel<<<BMC * 16, 256, 0, stream>>>(A1g, A2t, x1g, v2g, c3g, partial);
    final_kernel<<<512, 256, 0, stream>>>(x, b3, partial, out);
}

// Round 5
// 104.038 us; speedup vs baseline: 1.0391x; 1.0062x over previous
//
#include <hip/hip_runtime.h>

// B=4, M=8, N=128, D=32, K=2D=H=64
#define BMC 32
#define NNC 128
#define DDC 32
#define KKC 64
constexpr int ND = NNC * DDC;   // 4096
constexpr int NK = NNC * KKC;   // 8192
#define SMALLV 1e-8f

__device__ __forceinline__ float gelu_f(float v) {
    // tanh-gelu folded: gelu(v) = v - v * rcp(1 + exp2(v*(a*v^2+b)))
    float v2 = v * v;
    float p  = fmaf(0.1029432f, v2, 2.3022082f);
    float e  = __builtin_amdgcn_exp2f(v * p);
    float r  = __builtin_amdgcn_rcpf(e + 1.0f);
    return fmaf(-v, r, v);
}

// ---------------------------------------------------------------------------
// Kernel 1: fused stats + MLP1 + A1/A2. Grid = bm(32) x nt(16) = 512 x 256.
// ---------------------------------------------------------------------------
__global__ __launch_bounds__(256) void mlp_kernel(
    const float* __restrict__ x, const float* __restrict__ x_size,
    const float* __restrict__ W1a, const float* __restrict__ b1a,
    const float* __restrict__ W1b, const float* __restrict__ b1b,
    const float* __restrict__ W2a, const float* __restrict__ b2a,
    const float* __restrict__ W2b, const float* __restrict__ b2b,
    const float* __restrict__ w3,
    float* __restrict__ x1g, float* __restrict__ A1g, float* __restrict__ A2t,
    float* __restrict__ v2g, float* __restrict__ c3g)
{
    __shared__ float sW1a[DDC * KKC];   // 8 KB
    __shared__ float sW1b[KKC * DDC];   // 8 KB
    __shared__ float sW2a[DDC * KKC];   // 8 KB
    __shared__ float sXn[8 * DDC];
    __shared__ float sH[8 * KKC];
    __shared__ float sX1[8 * DDC];
    __shared__ float sB1a[KKC], sB2a[KKC], sB1b[DDC];
    __shared__ float sAny[NNC];
    __shared__ float sRed[4];

    const int t  = threadIdx.x;
    const int bm = blockIdx.x >> 4;
    const int nt = blockIdx.x & 15;
    const int n0 = nt * 8;
    const int w  = t >> 6;

    // Stage weights (512 float4 per matrix, 2 per thread)
    {
        const float4* a4 = (const float4*)W1a;
        const float4* b4 = (const float4*)W1b;
        const float4* c4 = (const float4*)W2a;
        float4* sa = (float4*)sW1a; float4* sb = (float4*)sW1b; float4* sc = (float4*)sW2a;
        sa[t] = a4[t]; sa[t + 256] = a4[t + 256];
        sb[t] = b4[t]; sb[t + 256] = b4[t + 256];
        sc[t] = c4[t]; sc[t + 256] = c4[t + 256];
    }
    if (t < KKC) { sB1a[t] = b1a[t]; sB2a[t] = b2a[t]; }
    if (t < DDC) { sB1b[t] = b1b[t]; }
    if (t < NNC) sAny[t] = 0.f;
    __syncthreads();

    // ---- per-(b,m) stats (redundant per block) ----
    const float4* xs4 = (const float4*)(x + (size_t)bm * ND);
    float4 v4[4];
    float lsum = 0.f;
    #pragma unroll
    for (int s = 0; s < 4; ++s) {
        int f = t + s * 256;
        float4 q = xs4[f];
        v4[s] = q;
        lsum += q.x + q.y + q.z + q.w;
        if (q.x != 0.f || q.y != 0.f || q.z != 0.f || q.w != 0.f) sAny[f >> 3] = 1.f;
    }
    #pragma unroll
    for (int off = 32; off; off >>= 1) lsum += __shfl_xor(lsum, off);
    if ((t & 63) == 0) sRed[w] = lsum;
    __syncthreads();
    const float denom = x_size[bm >> 3] * (float)DDC;
    const float mean  = (sRed[0] + sRed[1] + sRed[2] + sRed[3]) / denom;

    float lsq = 0.f;
    #pragma unroll
    for (int s = 0; s < 4; ++s) {
        int f = t + s * 256;
        float mk = sAny[f >> 3];
        float dx = v4[s].x - mean, dy = v4[s].y - mean;
        float dz = v4[s].z - mean, dw = v4[s].w - mean;
        lsq += mk * (dx * dx + dy * dy + dz * dz + dw * dw);
    }
    #pragma unroll
    for (int off = 32; off; off >>= 1) lsq += __shfl_xor(lsq, off);
    __syncthreads();
    if ((t & 63) == 0) sRed[w] = lsq;
    __syncthreads();
    const float sq  = sRed[0] + sRed[1] + sRed[2] + sRed[3];
    const float inv = 1.f / (sqrtf(sq / denom) + SMALLV);

    // ---- normalize own 8-row tile ----
    {
        float xv = x[(size_t)bm * ND + n0 * DDC + t];
        sXn[t] = (xv - mean) * inv * sAny[n0 + (t >> 5)];
    }
    __syncthreads();

    const int k = t & 63;

    // H = gelu(xn @ W1a + b1a): rows w, w+4
    #pragma unroll
    for (int r = 0; r < 2; ++r) {
        int n = w + r * 4;
        const float* xr = &sXn[n * DDC];
        float acc = sB1a[k];
        #pragma unroll
        for (int d = 0; d < DDC; ++d) acc = fmaf(xr[d], sW1a[d * KKC + k], acc);
        sH[n * KKC + k] = gelu_f(acc);
    }
    __syncthreads();

    // x1 = (H @ W1b + b1b) * mask
    {
        const int d2 = t & 31;
        const int n  = t >> 5;
        const float* hr = &sH[n * KKC];
        float acc = sB1b[d2];
        #pragma unroll
        for (int q = 0; q < KKC; ++q) acc = fmaf(hr[q], sW1b[q * DDC + d2], acc);
        float val = acc * sAny[n0 + n];
        sX1[n * DDC + d2] = val;
        x1g[(size_t)bm * ND + (n0 + n) * DDC + d2] = val;
    }
    __syncthreads();

    // A1 = x1@W2a + b2a ; A2 = xn@W2a (transposed store [k][j])
    #pragma unroll
    for (int r = 0; r < 2; ++r) {
        int n = w + r * 4;
        const float* x1r = &sX1[n * DDC];
        const float* xnr = &sXn[n * DDC];
        float a1 = sB2a[k], a2 = 0.f;
        #pragma unroll
        for (int d = 0; d < DDC; ++d) {
            a1 = fmaf(x1r[d], sW2a[d * KKC + k], a1);
            a2 = fmaf(xnr[d], sW2a[d * KKC + k], a2);
        }
        A1g[(size_t)bm * NK + (n0 + n) * KKC + k] = a1;
        A2t[(size_t)bm * NK + k * NNC + (n0 + n)] = a2;
    }

    if (blockIdx.x == 0) {
        // v2[k] = sum_h W2b[k][h]*w3[h], parallel over 256 threads
        int kk = t >> 2, hq = t & 3;
        float p = 0.f;
        #pragma unroll
        for (int h = 0; h < 16; ++h)
            p = fmaf(W2b[kk * KKC + hq * 16 + h], w3[hq * 16 + h], p);
        __syncthreads();           // sH free for reuse
        sH[t] = p;
        __syncthreads();
        if (hq == 0) v2g[kk] = sH[t] + sH[t + 1] + sH[t + 2] + sH[t + 3];
        if (t < 64) {
            float q = b2b[t] * w3[t];
            #pragma unroll
            for (int off = 32; off; off >>= 1) q += __shfl_xor(q, off);
            if (t == 0) c3g[0] = q;
        }
    }
}

// ---------------------------------------------------------------------------
// Kernel 2: pair interactions. Grid = bm(32) x jg(2) x ig(16) = 1024 blocks.
// Block covers 8 i x 64 j. Phase 1: wave = 2 i-chains, lane = j; all operand
// streams via LDS (DS pipelines, no SMEM drains). Phase 2: rank-1 update.
// Blocks fully past x_size exit immediately.
// ---------------------------------------------------------------------------
__global__ __launch_bounds__(256) void pair_kernel(
    const float* __restrict__ x_size,
    const float* __restrict__ A1g, const float* __restrict__ A2t,
    const float* __restrict__ x1g, const float* __restrict__ v2g,
    const float* __restrict__ c3g, float* __restrict__ partial)
{
    __shared__ float sA2[KKC * 64];   // [k][j] 16 KB
    __shared__ float sA1[8 * KKC];    // 2 KB
    __shared__ float sX1[8 * DDC];    // 1 KB
    __shared__ float sS[8 * 64];      // 2 KB
    __shared__ float sV2[KKC];

    const int t    = threadIdx.x;
    const int bm   = blockIdx.x >> 5;
    const int jg   = (blockIdx.x >> 4) & 1;
    const int ig   = blockIdx.x & 15;

    const int iN = (int)(x_size[bm >> 3] + 0.5f);
    if (ig * 8 >= iN || jg * 64 >= iN) return;   // fully-padded tile: skip

    const int wv   = t >> 6;
    const int lane = t & 63;

    // ---- stage A2 tile [k][j-local] (coalesced 256B rows) ----
    {
        const float* A2b = A2t + (size_t)bm * NK + jg * 64;
        float4* s4 = (float4*)sA2;
        #pragma unroll
        for (int s = 0; s < 4; ++s) {
            int idx = t + s * 256;          // float4 index
            int k = idx >> 4, f = idx & 15;
            s4[idx] = *(const float4*)(A2b + k * NNC + f * 4);
        }
    }
    // A1 rows (512 consecutive floats), x1 rows (256), v2
    {
        const float2* a1s = (const float2*)(A1g + (size_t)bm * NK + ig * 8 * KKC);
        ((float2*)sA1)[t] = a1s[t];
        sX1[t] = x1g[(size_t)bm * ND + ig * 8 * DDC + t];
        if (t < KKC) sV2[t] = v2g[t];
    }
    const float c3 = c3g[0];
    __syncthreads();

    // ---- phase 1: wave wv handles i-chains 2*wv, 2*wv+1 ----
    {
        const int i0 = wv * 2, i1 = i0 + 1;
        float S0 = c3, S1 = c3;
        #pragma unroll 8
        for (int k = 0; k < KKC; ++k) {
            float a2v = sA2[k * 64 + lane];
            float vk  = sV2[k];
            float a10 = sA1[i0 * KKC + k];
            float a11 = sA1[i1 * KKC + k];
            S0 = fmaf(gelu_f(a10 - a2v), vk, S0);
            S1 = fmaf(gelu_f(a11 - a2v), vk, S1);
        }
        sS[i0 * 64 + lane] = S0;
        sS[i1 * 64 + lane] = S1;
    }
    __syncthreads();

    // ---- phase 2: thread = (j = t>>2, dq = t&3), 8 d's each ----
    {
        const int j  = t >> 2;
        const int dq = t & 3;
        float acc[8];
        #pragma unroll
        for (int d = 0; d < 8; ++d) acc[d] = 0.f;
        #pragma unroll
        for (int i = 0; i < 8; ++i) {
            float Sv = sS[i * 64 + j];
            const float4* xf = (const float4*)&sX1[i * DDC + dq * 8];
            float4 xa = xf[0], xb = xf[1];
            acc[0] = fmaf(Sv, xa.x, acc[0]);
            acc[1] = fmaf(Sv, xa.y, acc[1]);
            acc[2] = fmaf(Sv, xa.z, acc[2]);
            acc[3] = fmaf(Sv, xa.w, acc[3]);
            acc[4] = fmaf(Sv, xb.x, acc[4]);
            acc[5] = fmaf(Sv, xb.y, acc[5]);
            acc[6] = fmaf(Sv, xb.z, acc[6]);
            acc[7] = fmaf(Sv, xb.w, acc[7]);
        }
        // partial layout: [bm][jg][ig][j-local][d]; thread-contiguous (t*8)
        float* pb = partial + ((size_t)((bm * 2 + jg) * 16 + ig)) * 2048 + t * 8;
        ((float4*)pb)[0] = make_float4(acc[0], acc[1], acc[2], acc[3]);
        ((float4*)pb)[1] = make_float4(acc[4], acc[5], acc[6], acc[7]);
    }
}

// ---------------------------------------------------------------------------
// Kernel 3: sum valid i-group partials, add b3 + residual, apply item mask.
// ---------------------------------------------------------------------------
__global__ __launch_bounds__(256) void final_kernel(
    const float* __restrict__ x, const float* __restrict__ x_size,
    const float* __restrict__ b3,
    const float* __restrict__ partial, float* __restrict__ out)
{
    const int gid = blockIdx.x * 256 + threadIdx.x;   // < 131072
    const int bm  = gid >> 12;
    const int rem = gid & 4095;                        // j*32 + d
    float xv = x[gid];
    unsigned long long bal = __ballot(xv != 0.f);
    int lane = threadIdx.x & 63;
    unsigned long long half = (lane < 32) ? (bal & 0xFFFFFFFFull) : (bal >> 32);
    if (half == 0ull) { out[gid] = 0.f; return; }

    const int iN  = (int)(x_size[bm >> 3] + 0.5f);
    const int nig = (iN + 7) >> 3;                     // valid i-groups (8..16)
    const int jgp = rem >> 11;                         // j-group (0/1)
    const size_t pb = ((size_t)((bm * 2 + jgp) * 16)) * 2048 + (rem & 2047);
    float sum = 0.f;
    for (int ig = 0; ig < nig; ++ig) sum += partial[pb + (size_t)ig * 2048];
    out[gid] = sum + b3[0] + xv;
}

extern "C" void kernel_launch(void* const* d_in, const int* in_sizes, int n_in,
                              void* d_out, int out_size, void* d_ws, size_t ws_size,
                              hipStream_t stream) {
    const float* x      = (const float*)d_in[0];
    const float* x_size = (const float*)d_in[1];
    const float* W1a    = (const float*)d_in[2];
    const float* b1a    = (const float*)d_in[3];
    const float* W1b    = (const float*)d_in[4];
    const float* b1b    = (const float*)d_in[5];
    const float* W2a    = (const float*)d_in[6];
    const float* b2a    = (const float*)d_in[7];
    const float* W2b    = (const float*)d_in[8];
    const float* b2b    = (const float*)d_in[9];
    const float* w3     = (const float*)d_in[10];
    const float* b3     = (const float*)d_in[11];
    float* out = (float*)d_out;

    float* ws      = (float*)d_ws;
    float* x1g     = ws;                       // 131072
    float* A1g     = x1g + (size_t)BMC * ND;   // 262144
    float* A2t     = A1g + (size_t)BMC * NK;   // 262144
    float* v2g     = A2t + (size_t)BMC * NK;   // 64
    float* c3g     = v2g + KKC;                // 1 (+63 pad)
    float* partial = c3g + 64;                 // 1024*2048 = 2097152 (8 MB)

    mlp_kernel<<<BMC * 16, 256, 0, stream>>>(x, x_size,
        W1a, b1a, W1b, b1b, W2a, b2a, W2b, b2b, w3,
        x1g, A1g, A2t, v2g, c3g);
    pair_kernel<<<BMC * 32, 256, 0, stream>>>(x_size, A1g, A2t, x1g, v2g, c3g, partial);
    final_kernel<<<512, 256, 0, stream>>>(x, x_size, b3, partial, out);
}